// Round 6
// baseline (65.418 us; speedup 1.0000x reference)
//
#include <hip/hip_runtime.h>
#include <math.h>

#define ALPHA_F 100.0f

constexpr int N_ = 32, C_ = 128, K_ = 64, S_ = 4096;
constexpr int NCHUNK = 16, SCHUNK = S_ / NCHUNK;  // 256
constexpr int ST = 128, NSUB = SCHUNK / ST;       // 2 subtiles of 128 pixels
constexpr int NT = 512;                           // 8 waves

typedef _Float16 f16;
typedef __attribute__((ext_vector_type(4))) _Float16 f16x4;
typedef __attribute__((ext_vector_type(8))) _Float16 f16x8;
typedef __attribute__((ext_vector_type(4))) float f32x4;

// LDS layout (bytes). All access patterns here are R3-validated (b128/b64 only,
// no tr-reads). xbh: x fp16 [c][136] (pad 8 u16 -> 16B-aligned rows, balanced
// banks). a_s: a' fp16 [k][136]. cls/chs: centroid lo/hi with octet^k swizzle.
constexpr int XBH = 0;        // 128*136*2 = 34816
constexpr int ASB = 34816;    // 64*136*2  = 17408 (f32 scr[1024] aliases base)
constexpr int CLS = 52224;    // cent-lo [64][128] u16, octet^(k&15) swz (16384)
constexpr int CHS = 68608;    // cent-hi k=16..63 [48][128] u16, same swz (12288)
constexpr int INV = 80896;    // f32 invn[128] (512)
constexpr int BIA = 81408;    // f32 bias[64]  (256)
constexpr int LDS_SZ = 81664; // 79.75 KB -> 2 blocks/CU (163328 <= 163840)

#define BARRIER() do { asm volatile("s_waitcnt lgkmcnt(0)" ::: "memory"); \
                       __builtin_amdgcn_s_barrier(); } while (0)

__global__ __launch_bounds__(NT, 4)
void nv_stage1(const float* __restrict__ x, const float* __restrict__ cent,
               float* __restrict__ vlad_part, float* __restrict__ asum_part) {
  __shared__ __align__(16) unsigned char lds[LDS_SZ];
  ushort* xbh  = (ushort*)(lds + XBH);
  ushort* a_s  = (ushort*)(lds + ASB);
  float*  scr  = (float*)(lds + ASB);
  ushort* cls  = (ushort*)(lds + CLS);
  ushort* chs  = (ushort*)(lds + CHS);
  float*  invn = (float*)(lds + INV);
  float*  bias_s = (float*)(lds + BIA);

  const int t = threadIdx.x;
  const int l = t & 63, w = t >> 6;
  const int l16 = l & 15, g = l >> 4;
  const int cq = t >> 4, so = t & 15;       // staging: c-quad, s-octet
  const int chunk = blockIdx.x, n = blockIdx.y;
  const int sb = w * 16, cb = w * 16;       // wave's s-tile (GEMM1) / c-tile (GEMM2)

  const float* xg = x + (size_t)n * C_ * S_ + (size_t)chunk * SCHUNK;

  // ---- prologue: stage subtile 0 into registers
  float xr[4][8];
  #pragma unroll
  for (int i = 0; i < 4; ++i) {
    const float* p = xg + (size_t)(cq * 4 + i) * S_ + so * 8;
    float4 u = *(const float4*)p, v = *(const float4*)(p + 4);
    xr[i][0] = u.x; xr[i][1] = u.y; xr[i][2] = u.z; xr[i][3] = u.w;
    xr[i][4] = v.x; xr[i][5] = v.y; xr[i][6] = v.z; xr[i][7] = v.w;
  }

  // bias partials (k = l, c-range w*16..+16) -> scr
  {
    const float* cr = cent + l * C_ + w * 16;
    float ss = 0.f;
    #pragma unroll
    for (int h = 0; h < 4; ++h) {
      float4 v = *(const float4*)(cr + h * 4);
      ss += v.x * v.x + v.y * v.y + v.z * v.z + v.w * v.w;
    }
    scr[w * 64 + l] = ss;
  }
  // cent-lo: k = t>>3, 16 c at (t&7)*16; lo = c - (float)hi
  {
    const int k = t >> 3, c7 = t & 7;
    const float* cr = cent + k * C_ + c7 * 16;
    f16x8 lo0, lo1;
    #pragma unroll
    for (int h = 0; h < 8; ++h) {
      float v0 = cr[h], v1 = cr[8 + h];
      lo0[h] = (f16)(v0 - (float)((f16)v0));
      lo1[h] = (f16)(v1 - (float)((f16)v1));
    }
    *(f16x8*)&cls[k * 128 + ((2 * c7) ^ (k & 15)) * 8]     = lo0;
    *(f16x8*)&cls[k * 128 + ((2 * c7 + 1) ^ (k & 15)) * 8] = lo1;
  }
  // cent-hi rows k=16..63 -> chs
  if (t < 384) {
    const int kl = t >> 3, c7 = t & 7;   // kl 0..47 -> k = 16+kl
    const float* cr = cent + (16 + kl) * C_ + c7 * 16;
    f16x8 h0v, h1v;
    #pragma unroll
    for (int h = 0; h < 8; ++h) { h0v[h] = (f16)cr[h]; h1v[h] = (f16)cr[8 + h]; }
    *(f16x8*)&chs[kl * 128 + ((2 * c7) ^ (kl & 15)) * 8]     = h0v;
    *(f16x8*)&chs[kl * 128 + ((2 * c7 + 1) ^ (kl & 15)) * 8] = h1v;
  }
  // cent-hi rows k=0..15 in registers (B-frag for nt2=0)
  f16x8 chf0[4];
  #pragma unroll
  for (int ks = 0; ks < 4; ++ks) {
    const float* cr = cent + l16 * C_ + ks * 32 + g * 8;
    #pragma unroll
    for (int h = 0; h < 8; ++h) chf0[ks][h] = (f16)cr[h];
  }
  __syncthreads();
  if (t < 64) {
    float ss = 0.f;
    #pragma unroll
    for (int q = 0; q < 8; ++q) ss += scr[q * 64 + t];
    bias_s[t] = -ALPHA_F * sqrtf(ss);
  }
  __syncthreads();
  float bias_r[4];
  #pragma unroll
  for (int nt2 = 0; nt2 < 4; ++nt2) bias_r[nt2] = bias_s[nt2 * 16 + l16];

  f32x4 acc2[4];
  #pragma unroll
  for (int nt2 = 0; nt2 < 4; ++nt2) { f32x4 z = {0.f,0.f,0.f,0.f}; acc2[nt2] = z; }
  float asum_acc[4] = {0.f, 0.f, 0.f, 0.f};

  for (int st = 0; st < NSUB; ++st) {
    // ---- P0: ssq partials (shuffle-reduced) + fp16 convert + xbh [c][s] write
    {
      float ssj[8];
      #pragma unroll
      for (int j = 0; j < 8; ++j) {
        ssj[j] = xr[0][j]*xr[0][j] + xr[1][j]*xr[1][j] + xr[2][j]*xr[2][j] + xr[3][j]*xr[3][j];
        ssj[j] += __shfl_xor(ssj[j], 16);
        ssj[j] += __shfl_xor(ssj[j], 32);
      }
      if (g == 0) {
        *(float4*)&scr[w * 128 + so * 8]     = make_float4(ssj[0], ssj[1], ssj[2], ssj[3]);
        *(float4*)&scr[w * 128 + so * 8 + 4] = make_float4(ssj[4], ssj[5], ssj[6], ssj[7]);
      }
      #pragma unroll
      for (int i = 0; i < 4; ++i) {
        f16x8 r;
        #pragma unroll
        for (int j = 0; j < 8; ++j) r[j] = (f16)xr[i][j];
        *(f16x8*)&xbh[(cq * 4 + i) * 136 + so * 8] = r;
      }
    }
    BARRIER();  // B1
    if (t < ST) {
      float s2 = 0.f;
      #pragma unroll
      for (int q = 0; q < 8; ++q) s2 += scr[q * 128 + t];
      invn[t] = 1.0f / fmaxf(sqrtf(s2), 1e-12f);
    }
    BARRIER();  // B2

    // ---- D: GEMM1 A from exact global reloads (in-reg hi/lo), softmax, a' write
    {
      f32x4 acc1[4];
      #pragma unroll
      for (int nt2 = 0; nt2 < 4; ++nt2) { f32x4 z = {0.f,0.f,0.f,0.f}; acc1[nt2] = z; }
      #pragma unroll
      for (int ks = 0; ks < 4; ++ks) {
        float xa[8];
        const float* pcol = xg + st * ST + sb + l16 + (size_t)(ks * 32 + g * 8) * S_;
        #pragma unroll
        for (int j = 0; j < 8; ++j) xa[j] = pcol[(size_t)j * S_];
        f16x8 ah, al;
        #pragma unroll
        for (int j = 0; j < 8; ++j) {
          f16 h = (f16)xa[j];
          ah[j] = h;
          al[j] = (f16)(xa[j] - (float)h);
        }
        f16x8 bh[4], bl[4];
        bh[0] = chf0[ks];
        #pragma unroll
        for (int nt2 = 1; nt2 < 4; ++nt2)
          bh[nt2] = *(const f16x8*)&chs[((nt2 - 1) * 16 + l16) * 128 + (((ks * 4 + g) ^ l16) * 8)];
        #pragma unroll
        for (int nt2 = 0; nt2 < 4; ++nt2)
          bl[nt2] = *(const f16x8*)&cls[(nt2 * 16 + l16) * 128 + (((ks * 4 + g) ^ l16) * 8)];
        #pragma unroll
        for (int nt2 = 0; nt2 < 4; ++nt2) {
          acc1[nt2] = __builtin_amdgcn_mfma_f32_16x16x32_f16(ah, bh[nt2], acc1[nt2], 0, 0, 0);
          acc1[nt2] = __builtin_amdgcn_mfma_f32_16x16x32_f16(ah, bl[nt2], acc1[nt2], 0, 0, 0);
          acc1[nt2] = __builtin_amdgcn_mfma_f32_16x16x32_f16(al, bh[nt2], acc1[nt2], 0, 0, 0);
        }
      }
      float inv4[4];
      #pragma unroll
      for (int i = 0; i < 4; ++i) inv4[i] = invn[sb + 4 * g + i];
      float v[4][4], mx[4], sm[4];
      #pragma unroll
      for (int nt2 = 0; nt2 < 4; ++nt2)
        #pragma unroll
        for (int i = 0; i < 4; ++i)
          v[nt2][i] = 2.f * ALPHA_F * acc1[nt2][i] * inv4[i] + bias_r[nt2];
      #pragma unroll
      for (int i = 0; i < 4; ++i) {
        mx[i] = fmaxf(fmaxf(v[0][i], v[1][i]), fmaxf(v[2][i], v[3][i]));
        mx[i] = fmaxf(mx[i], __shfl_xor(mx[i], 1));
        mx[i] = fmaxf(mx[i], __shfl_xor(mx[i], 2));
        mx[i] = fmaxf(mx[i], __shfl_xor(mx[i], 4));
        mx[i] = fmaxf(mx[i], __shfl_xor(mx[i], 8));
        sm[i] = 0.f;
      }
      #pragma unroll
      for (int nt2 = 0; nt2 < 4; ++nt2)
        #pragma unroll
        for (int i = 0; i < 4; ++i) { float e = __expf(v[nt2][i] - mx[i]); v[nt2][i] = e; sm[i] += e; }
      #pragma unroll
      for (int i = 0; i < 4; ++i) {
        sm[i] += __shfl_xor(sm[i], 1); sm[i] += __shfl_xor(sm[i], 2);
        sm[i] += __shfl_xor(sm[i], 4); sm[i] += __shfl_xor(sm[i], 8);
        sm[i] = 1.0f / sm[i];
      }
      #pragma unroll
      for (int nt2 = 0; nt2 < 4; ++nt2) {
        float a0 = v[nt2][0] * sm[0], a1 = v[nt2][1] * sm[1];
        float a2 = v[nt2][2] * sm[2], a3 = v[nt2][3] * sm[3];
        asum_acc[nt2] += a0 + a1 + a2 + a3;
        f16x4 av;
        av[0] = (f16)(a0 * inv4[0]); av[1] = (f16)(a1 * inv4[1]);
        av[2] = (f16)(a2 * inv4[2]); av[3] = (f16)(a3 * inv4[3]);
        *(f16x4*)&a_s[(nt2 * 16 + l16) * 136 + sb + g * 4] = av;
      }
    }
    BARRIER();  // B3

    // ---- E: GEMM2 D[c][k] += x[c][s] . a'[k][s]; prefetch next subtile
    if (st + 1 < NSUB) {
      const float* pg = xg + (st + 1) * ST + so * 8;
      #pragma unroll
      for (int i = 0; i < 4; ++i) {
        const float* p = pg + (size_t)(cq * 4 + i) * S_;
        float4 u = *(const float4*)p, vq = *(const float4*)(p + 4);
        xr[i][0] = u.x; xr[i][1] = u.y; xr[i][2] = u.z; xr[i][3] = u.w;
        xr[i][4] = vq.x; xr[i][5] = vq.y; xr[i][6] = vq.z; xr[i][7] = vq.w;
      }
    }
    #pragma unroll
    for (int ks = 0; ks < 4; ++ks) {
      f16x8 xq = *(const f16x8*)&xbh[(cb + l16) * 136 + ks * 32 + g * 8];
      #pragma unroll
      for (int nt2 = 0; nt2 < 4; ++nt2) {
        f16x8 pa = *(const f16x8*)&a_s[(nt2 * 16 + l16) * 136 + ks * 32 + g * 8];
        acc2[nt2] = __builtin_amdgcn_mfma_f32_16x16x32_f16(xq, pa, acc2[nt2], 0, 0, 0);
      }
    }
    BARRIER();  // B4
  }

  // ---- epilogue: acc2[nt2][i] = vlad[k = nt2*16 + l16][c = cb + 4g + i]
  #pragma unroll
  for (int nt2 = 0; nt2 < 4; ++nt2) {
    float vv = asum_acc[nt2];
    vv += __shfl_xor(vv, 16); vv += __shfl_xor(vv, 32);
    if (g == 0) scr[w * 64 + nt2 * 16 + l16] = vv;
  }
  const size_t base = (size_t)(n * NCHUNK + chunk) * (K_ * C_);
  #pragma unroll
  for (int nt2 = 0; nt2 < 4; ++nt2) {
    float4 o = make_float4(acc2[nt2][0], acc2[nt2][1], acc2[nt2][2], acc2[nt2][3]);
    *(float4*)&vlad_part[base + (size_t)(nt2 * 16 + l16) * C_ + cb + g * 4] = o;
  }
  BARRIER();
  if (t < 64) {
    float s2 = 0.f;
    #pragma unroll
    for (int q = 0; q < 8; ++q) s2 += scr[q * 64 + t];
    asum_part[(n * NCHUNK + chunk) * K_ + t] = s2;
  }
}

// ---- stage 2a: reduce chunks, subtract, intra-normalize (256 blocks) ----
__global__ __launch_bounds__(256)
void nv_stage2a(const float* __restrict__ vlad_part, const float* __restrict__ asum_part,
                const float* __restrict__ cent, float* __restrict__ vlad_n,
                float* __restrict__ rssq) {
  const int t = threadIdx.x, b = blockIdx.x;
  const int n = b >> 3, k8 = (b & 7) * 8;
  const int kl = t >> 5, c4 = (t & 31) * 4;
  const int k = k8 + kl;
  float as = 0.f;
  for (int ch = 0; ch < NCHUNK; ++ch) as += asum_part[(n * NCHUNK + ch) * K_ + k];
  float4 acc = make_float4(0.f, 0.f, 0.f, 0.f);
  for (int ch = 0; ch < NCHUNK; ++ch) {
    float4 v = *(const float4*)&vlad_part[((size_t)(n * NCHUNK + ch) * K_ + k) * C_ + c4];
    acc.x += v.x; acc.y += v.y; acc.z += v.z; acc.w += v.w;
  }
  float4 cw = *(const float4*)&cent[k * C_ + c4];
  acc.x -= as * cw.x; acc.y -= as * cw.y; acc.z -= as * cw.z; acc.w -= as * cw.w;
  float ssq = acc.x * acc.x + acc.y * acc.y + acc.z * acc.z + acc.w * acc.w;
  #pragma unroll
  for (int m = 1; m <= 16; m <<= 1) ssq += __shfl_xor(ssq, m);
  float scl = 1.0f / fmaxf(sqrtf(ssq), 1e-12f);
  *(float4*)&vlad_n[(size_t)n * (K_ * C_) + k * C_ + c4] =
      make_float4(acc.x * scl, acc.y * scl, acc.z * scl, acc.w * scl);
  if ((t & 31) == 0) rssq[n * K_ + k] = ssq * scl * scl;
}

// ---- stage 2b: global L2 normalize (32 blocks) ----
__global__ __launch_bounds__(256)
void nv_stage2b(const float* __restrict__ vlad_n, const float* __restrict__ rssq,
                float* __restrict__ out) {
  const int t = threadIdx.x, n = blockIdx.x;
  float tot = 0.f;
  for (int k2 = 0; k2 < K_; ++k2) tot += rssq[n * K_ + k2];
  const float rfin = 1.0f / fmaxf(sqrtf(tot), 1e-12f);
  #pragma unroll
  for (int r = 0; r < 8; ++r) {
    int idx = t * 4 + r * 1024;
    float4 v = *(const float4*)&vlad_n[(size_t)n * (K_ * C_) + idx];
    *(float4*)&out[(size_t)n * (K_ * C_) + idx] =
        make_float4(v.x * rfin, v.y * rfin, v.z * rfin, v.w * rfin);
  }
}

extern "C" void kernel_launch(void* const* d_in, const int* in_sizes, int n_in,
                              void* d_out, int out_size, void* d_ws, size_t ws_size,
                              hipStream_t stream) {
  const float* x    = (const float*)d_in[0];   // [32,128,64,64] fp32
  const float* cent = (const float*)d_in[1];   // [64,128] fp32
  float* out = (float*)d_out;                  // [32, 8192] fp32

  float* vlad_part = (float*)d_ws;                                     // 32*16*8192
  float* asum_part = vlad_part + (size_t)N_ * NCHUNK * K_ * C_;        // 32*16*64
  float* vlad_n    = asum_part + (size_t)N_ * NCHUNK * K_;             // 32*8192
  float* rssq      = vlad_n + (size_t)N_ * K_ * C_;                    // 32*64

  dim3 g1(NCHUNK, N_);
  nv_stage1<<<g1, NT, 0, stream>>>(x, cent, vlad_part, asum_part);
  nv_stage2a<<<N_ * 8, 256, 0, stream>>>(vlad_part, asum_part, cent, vlad_n, rssq);
  nv_stage2b<<<N_, 256, 0, stream>>>(vlad_n, rssq, out);
}

// Round 8
// 60.751 us; speedup vs baseline: 1.0768x; 1.0768x over previous
//
#include <hip/hip_runtime.h>
#include <math.h>

#define ALPHA_F 100.0f

constexpr int N_ = 32, C_ = 128, K_ = 64, S_ = 4096;
constexpr int NCHUNK = 16, SCHUNK = S_ / NCHUNK;  // 256
constexpr int ST = 128, NSUB = SCHUNK / ST;       // 2 subtiles of 128 pixels
constexpr int NT = 512;                           // 8 waves

typedef _Float16 f16;
typedef __attribute__((ext_vector_type(4))) _Float16 f16x4;
typedef __attribute__((ext_vector_type(8))) _Float16 f16x8;
typedef __attribute__((ext_vector_type(4))) float f32x4;

// LDS layout (bytes).
// xbh: x fp16 [c=128][132 s-slots]; epilogue reuses region as f32 [64][132] vlad stage.
// a_s: a' fp16 [k=64][136]; prologue/epilogue alias first 2KB as f32 scr.
// cls/chs: centroid lo / hi(k=16..63), octet^k swizzle (R6-validated).
constexpr int XBH = 0;        // 128*132*2 = 33792  (== 64*132*4 epilogue stage)
constexpr int ASB = 33792;    // 64*136*2  = 17408
constexpr int CLS = 51200;    // 16384
constexpr int CHS = 67584;    // 12288
constexpr int BIA = 79872;    // 256
constexpr int LDS_SZ = 80128; // 2 blocks/CU (160256 <= 163840)

#define BARRIER() do { asm volatile("s_waitcnt lgkmcnt(0)" ::: "memory"); \
                       __builtin_amdgcn_s_barrier(); } while (0)

__global__ __launch_bounds__(NT, 4)
void nv_stage1(const float* __restrict__ x, const float* __restrict__ cent,
               float* __restrict__ vlad_part, float* __restrict__ asum_part) {
  __shared__ __align__(16) unsigned char lds[LDS_SZ];
  ushort* xbh  = (ushort*)(lds + XBH);
  ushort* a_s  = (ushort*)(lds + ASB);
  float*  scr  = (float*)(lds + ASB);
  ushort* cls  = (ushort*)(lds + CLS);
  ushort* chs  = (ushort*)(lds + CHS);
  float*  bias_s = (float*)(lds + BIA);

  const int t = threadIdx.x;
  const int l = t & 63, w = t >> 6;
  const int l16 = l & 15, g = l >> 4;
  const int chunk = blockIdx.x, n = blockIdx.y;
  const int sb = w * 16, cb = w * 16;     // wave's s-tile (GEMM1) / c-tile (GEMM2)

  const float* xg = x + (size_t)n * C_ * S_ + (size_t)chunk * SCHUNK;
  const float* xcol0 = xg + sb + l16;     // lane's pixel column

  // ---- prologue: stage subtile 0 as hi/lo A-fragments (x read ONCE)
  f16x8 ah[4], al[4];
  float inv_cur;
  {
    float ss = 0.f;
    #pragma unroll
    for (int ks = 0; ks < 4; ++ks) {
      const float* p = xcol0 + (size_t)(ks * 32 + g * 8) * S_;
      #pragma unroll
      for (int j = 0; j < 8; ++j) {
        float v = p[(size_t)j * S_];
        ss += v * v;
        f16 h = (f16)v;
        ah[ks][j] = h;
        al[ks][j] = (f16)(v - (float)h);
      }
    }
    ss += __shfl_xor(ss, 16);
    ss += __shfl_xor(ss, 32);
    inv_cur = 1.0f / fmaxf(sqrtf(ss), 1e-12f);
  }

  // bias partials (k = l, c-range w*16..+16) -> scr (consumed before loop)
  {
    const float* cr = cent + l * C_ + w * 16;
    float ss = 0.f;
    #pragma unroll
    for (int h = 0; h < 4; ++h) {
      float4 v = *(const float4*)(cr + h * 4);
      ss += v.x * v.x + v.y * v.y + v.z * v.z + v.w * v.w;
    }
    scr[w * 64 + l] = ss;
  }
  // cent-lo: k = t>>3, 16 c at (t&7)*16; lo = c - (float)hi   (R6-validated)
  {
    const int k = t >> 3, c7 = t & 7;
    const float* cr = cent + k * C_ + c7 * 16;
    f16x8 lo0, lo1;
    #pragma unroll
    for (int h = 0; h < 8; ++h) {
      float v0 = cr[h], v1 = cr[8 + h];
      lo0[h] = (f16)(v0 - (float)((f16)v0));
      lo1[h] = (f16)(v1 - (float)((f16)v1));
    }
    *(f16x8*)&cls[k * 128 + ((2 * c7) ^ (k & 15)) * 8]     = lo0;
    *(f16x8*)&cls[k * 128 + ((2 * c7 + 1) ^ (k & 15)) * 8] = lo1;
  }
  // cent-hi rows k=16..63 -> chs   (R6-validated)
  if (t < 384) {
    const int kl = t >> 3, c7 = t & 7;
    const float* cr = cent + (16 + kl) * C_ + c7 * 16;
    f16x8 h0v, h1v;
    #pragma unroll
    for (int h = 0; h < 8; ++h) { h0v[h] = (f16)cr[h]; h1v[h] = (f16)cr[8 + h]; }
    *(f16x8*)&chs[kl * 128 + ((2 * c7) ^ (kl & 15)) * 8]     = h0v;
    *(f16x8*)&chs[kl * 128 + ((2 * c7 + 1) ^ (kl & 15)) * 8] = h1v;
  }
  // cent-hi rows k=0..15 in registers (B-frag nt2=0)
  f16x8 chf0[4];
  #pragma unroll
  for (int ks = 0; ks < 4; ++ks) {
    const float* cr = cent + l16 * C_ + ks * 32 + g * 8;
    #pragma unroll
    for (int h = 0; h < 8; ++h) chf0[ks][h] = (f16)cr[h];
  }
  __syncthreads();
  if (t < 64) {
    float ss = 0.f;
    #pragma unroll
    for (int q = 0; q < 8; ++q) ss += scr[q * 64 + t];
    bias_s[t] = -ALPHA_F * sqrtf(ss);
  }
  __syncthreads();
  float bias_r[4];
  #pragma unroll
  for (int nt2 = 0; nt2 < 4; ++nt2) bias_r[nt2] = bias_s[nt2 * 16 + l16];

  f32x4 acc2[4];
  #pragma unroll
  for (int nt2 = 0; nt2 < 4; ++nt2) { f32x4 z = {0.f,0.f,0.f,0.f}; acc2[nt2] = z; }
  float asum_acc[4] = {0.f, 0.f, 0.f, 0.f};

  for (int st = 0; st < NSUB; ++st) {
    // ---- P0: write xbh [c][s] from A-frag regs (scalar u16)
    {
      union { f16x8 v; ushort u[8]; } cv;
      #pragma unroll
      for (int ks = 0; ks < 4; ++ks) {
        cv.v = ah[ks];
        #pragma unroll
        for (int j = 0; j < 8; ++j)
          xbh[(ks * 32 + g * 8 + j) * 132 + sb + l16] = cv.u[j];
      }
    }

    // ---- D: GEMM1 (ah*bh + ah*bl + al*bh) from regs+LDS; softmax; a' -> a_s
    {
      f32x4 acc1[4];
      #pragma unroll
      for (int nt2 = 0; nt2 < 4; ++nt2) { f32x4 z = {0.f,0.f,0.f,0.f}; acc1[nt2] = z; }
      #pragma unroll
      for (int ks = 0; ks < 4; ++ks) {
        f16x8 bh[4], bl[4];
        bh[0] = chf0[ks];
        #pragma unroll
        for (int nt2 = 1; nt2 < 4; ++nt2)
          bh[nt2] = *(const f16x8*)&chs[((nt2 - 1) * 16 + l16) * 128 + (((ks * 4 + g) ^ l16) * 8)];
        #pragma unroll
        for (int nt2 = 0; nt2 < 4; ++nt2)
          bl[nt2] = *(const f16x8*)&cls[(nt2 * 16 + l16) * 128 + (((ks * 4 + g) ^ l16) * 8)];
        #pragma unroll
        for (int nt2 = 0; nt2 < 4; ++nt2) {
          acc1[nt2] = __builtin_amdgcn_mfma_f32_16x16x32_f16(ah[ks], bh[nt2], acc1[nt2], 0, 0, 0);
          acc1[nt2] = __builtin_amdgcn_mfma_f32_16x16x32_f16(ah[ks], bl[nt2], acc1[nt2], 0, 0, 0);
          acc1[nt2] = __builtin_amdgcn_mfma_f32_16x16x32_f16(al[ks], bh[nt2], acc1[nt2], 0, 0, 0);
        }
      }
      // inv for D-row pixels s = sb + 4g + i: lane (4g+i) holds that pixel's inv
      float inv4[4];
      #pragma unroll
      for (int i = 0; i < 4; ++i) inv4[i] = __shfl(inv_cur, 4 * g + i, 64);
      float v[4][4], mx[4], sm[4];
      #pragma unroll
      for (int nt2 = 0; nt2 < 4; ++nt2)
        #pragma unroll
        for (int i = 0; i < 4; ++i)
          v[nt2][i] = 2.f * ALPHA_F * acc1[nt2][i] * inv4[i] + bias_r[nt2];
      #pragma unroll
      for (int i = 0; i < 4; ++i) {
        mx[i] = fmaxf(fmaxf(v[0][i], v[1][i]), fmaxf(v[2][i], v[3][i]));
        mx[i] = fmaxf(mx[i], __shfl_xor(mx[i], 1));
        mx[i] = fmaxf(mx[i], __shfl_xor(mx[i], 2));
        mx[i] = fmaxf(mx[i], __shfl_xor(mx[i], 4));
        mx[i] = fmaxf(mx[i], __shfl_xor(mx[i], 8));
        sm[i] = 0.f;
      }
      #pragma unroll
      for (int nt2 = 0; nt2 < 4; ++nt2)
        #pragma unroll
        for (int i = 0; i < 4; ++i) { float e = __expf(v[nt2][i] - mx[i]); v[nt2][i] = e; sm[i] += e; }
      #pragma unroll
      for (int i = 0; i < 4; ++i) {
        sm[i] += __shfl_xor(sm[i], 1); sm[i] += __shfl_xor(sm[i], 2);
        sm[i] += __shfl_xor(sm[i], 4); sm[i] += __shfl_xor(sm[i], 8);
        sm[i] = 1.0f / sm[i];
      }
      #pragma unroll
      for (int nt2 = 0; nt2 < 4; ++nt2) {
        float a0 = v[nt2][0] * sm[0], a1 = v[nt2][1] * sm[1];
        float a2 = v[nt2][2] * sm[2], a3 = v[nt2][3] * sm[3];
        asum_acc[nt2] += a0 + a1 + a2 + a3;
        f16x4 av;
        av[0] = (f16)(a0 * inv4[0]); av[1] = (f16)(a1 * inv4[1]);
        av[2] = (f16)(a2 * inv4[2]); av[3] = (f16)(a3 * inv4[3]);
        *(f16x4*)&a_s[(nt2 * 16 + l16) * 136 + sb + g * 4] = av;
      }
    }
    BARRIER();  // xbh + a_s ready for all waves

    // ---- E: GEMM2 D[c][k] += x[c][s] . a'[k][s]  (R6-validated mapping)
    #pragma unroll
    for (int ks = 0; ks < 4; ++ks) {
      union { f16x8 v; uint2 p[2]; } xu;
      xu.p[0] = *(const uint2*)&xbh[(cb + l16) * 132 + ks * 32 + g * 8];
      xu.p[1] = *(const uint2*)&xbh[(cb + l16) * 132 + ks * 32 + g * 8 + 4];
      #pragma unroll
      for (int nt2 = 0; nt2 < 4; ++nt2) {
        f16x8 pa = *(const f16x8*)&a_s[(nt2 * 16 + l16) * 136 + ks * 32 + g * 8];
        acc2[nt2] = __builtin_amdgcn_mfma_f32_16x16x32_f16(xu.v, pa, acc2[nt2], 0, 0, 0);
      }
    }
    // prefetch next subtile hi/lo A-frags, overlapped with MFMA drain
    if (st + 1 < NSUB) {
      const float* xc = xcol0 + (st + 1) * ST;
      float ss = 0.f;
      #pragma unroll
      for (int ks = 0; ks < 4; ++ks) {
        const float* p = xc + (size_t)(ks * 32 + g * 8) * S_;
        #pragma unroll
        for (int j = 0; j < 8; ++j) {
          float v = p[(size_t)j * S_];
          ss += v * v;
          f16 h = (f16)v;
          ah[ks][j] = h;
          al[ks][j] = (f16)(v - (float)h);
        }
      }
      ss += __shfl_xor(ss, 16);
      ss += __shfl_xor(ss, 32);
      inv_cur = 1.0f / fmaxf(sqrtf(ss), 1e-12f);
    }
    BARRIER();  // xbh/a_s consumed; safe to overwrite next iteration
  }

  // ---- epilogue: stage acc2 (R6 mapping: k=nt2*16+l16, c=cb+4g+i) + asum
  {
    float* vst = (float*)(lds + XBH);   // f32 [64][132] = 33792 B (xbh free now)
    #pragma unroll
    for (int nt2 = 0; nt2 < 4; ++nt2) {
      float4 o = make_float4(acc2[nt2][0], acc2[nt2][1], acc2[nt2][2], acc2[nt2][3]);
      *(float4*)&vst[(nt2 * 16 + l16) * 132 + cb + 4 * g] = o;
      float vv = asum_acc[nt2];
      vv += __shfl_xor(vv, 16); vv += __shfl_xor(vv, 32);
      if (g == 0) scr[w * 64 + nt2 * 16 + l16] = vv;
    }
    BARRIER();
    const size_t base = (size_t)(n * NCHUNK + chunk) * (K_ * C_);
    #pragma unroll
    for (int it = 0; it < 4; ++it) {
      int f = t + it * 512;              // float4 slot in [0,2048)
      int k = f >> 5, cs = (f & 31) * 4;
      float4 v = *(float4*)&vst[k * 132 + cs];
      *(float4*)&vlad_part[base + (size_t)k * C_ + cs] = v;   // contiguous lines
    }
    if (t < 64) {
      float s2 = 0.f;
      #pragma unroll
      for (int q = 0; q < 8; ++q) s2 += scr[q * 64 + t];
      asum_part[(n * NCHUNK + chunk) * K_ + t] = s2;
    }
  }
}

// ---- stage 2a: reduce chunks, subtract, intra-normalize (256 blocks) ----
__global__ __launch_bounds__(256)
void nv_stage2a(const float* __restrict__ vlad_part, const float* __restrict__ asum_part,
                const float* __restrict__ cent, float* __restrict__ vlad_n,
                float* __restrict__ rssq) {
  const int t = threadIdx.x, b = blockIdx.x;
  const int n = b >> 3, k8 = (b & 7) * 8;
  const int kl = t >> 5, c4 = (t & 31) * 4;
  const int k = k8 + kl;
  float as = 0.f;
  for (int ch = 0; ch < NCHUNK; ++ch) as += asum_part[(n * NCHUNK + ch) * K_ + k];
  float4 acc = make_float4(0.f, 0.f, 0.f, 0.f);
  for (int ch = 0; ch < NCHUNK; ++ch) {
    float4 v = *(const float4*)&vlad_part[((size_t)(n * NCHUNK + ch) * K_ + k) * C_ + c4];
    acc.x += v.x; acc.y += v.y; acc.z += v.z; acc.w += v.w;
  }
  float4 cw = *(const float4*)&cent[k * C_ + c4];
  acc.x -= as * cw.x; acc.y -= as * cw.y; acc.z -= as * cw.z; acc.w -= as * cw.w;
  float ssq = acc.x * acc.x + acc.y * acc.y + acc.z * acc.z + acc.w * acc.w;
  #pragma unroll
  for (int m = 1; m <= 16; m <<= 1) ssq += __shfl_xor(ssq, m);
  float scl = 1.0f / fmaxf(sqrtf(ssq), 1e-12f);
  *(float4*)&vlad_n[(size_t)n * (K_ * C_) + k * C_ + c4] =
      make_float4(acc.x * scl, acc.y * scl, acc.z * scl, acc.w * scl);
  if ((t & 31) == 0) rssq[n * K_ + k] = ssq * scl * scl;
}

// ---- stage 2b: global L2 normalize (32 blocks) ----
__global__ __launch_bounds__(256)
void nv_stage2b(const float* __restrict__ vlad_n, const float* __restrict__ rssq,
                float* __restrict__ out) {
  const int t = threadIdx.x, n = blockIdx.x;
  float tot = 0.f;
  for (int k2 = 0; k2 < K_; ++k2) tot += rssq[n * K_ + k2];
  const float rfin = 1.0f / fmaxf(sqrtf(tot), 1e-12f);
  #pragma unroll
  for (int r = 0; r < 8; ++r) {
    int idx = t * 4 + r * 1024;
    float4 v = *(const float4*)&vlad_n[(size_t)n * (K_ * C_) + idx];
    *(float4*)&out[(size_t)n * (K_ * C_) + idx] =
        make_float4(v.x * rfin, v.y * rfin, v.z * rfin, v.w * rfin);
  }
}

extern "C" void kernel_launch(void* const* d_in, const int* in_sizes, int n_in,
                              void* d_out, int out_size, void* d_ws, size_t ws_size,
                              hipStream_t stream) {
  const float* x    = (const float*)d_in[0];   // [32,128,64,64] fp32
  const float* cent = (const float*)d_in[1];   // [64,128] fp32
  float* out = (float*)d_out;                  // [32, 8192] fp32

  float* vlad_part = (float*)d_ws;                                     // 32*16*8192
  float* asum_part = vlad_part + (size_t)N_ * NCHUNK * K_ * C_;        // 32*16*64
  float* vlad_n    = asum_part + (size_t)N_ * NCHUNK * K_;             // 32*8192
  float* rssq      = vlad_n + (size_t)N_ * K_ * C_;                    // 32*64

  dim3 g1(NCHUNK, N_);
  nv_stage1<<<g1, NT, 0, stream>>>(x, cent, vlad_part, asum_part);
  nv_stage2a<<<N_ * 8, 256, 0, stream>>>(vlad_part, asum_part, cent, vlad_n, rssq);
  nv_stage2b<<<N_, 256, 0, stream>>>(vlad_n, rssq, out);
}